// Round 9
// baseline (179.501 us; speedup 1.0000x reference)
//
#include <hip/hip_runtime.h>

#define PI2 6.28318530717958647692f

// ===========================================================================
// Kernel 1: per (b,t) plane forward DFT restricted to kept modes.
// (UNCHANGED from r8, measured <= 40.4us.)
// Conjugate symmetry: X real => A2[128-kx][w] = conj(A2[kx][w]): phase 1
// computes kx = 0..16 only; phase 2 derives kxi>=16 by conjugation.
// Phase 1: register twiddles (exact (-i)^j refresh at h=32), X streamed
//   through a 4-buffer LDS ring (8-row chunks, depth-3 prefetch).
// Phase 2: thread = (kxi 0..31, t 0..7); ky-twiddles in registers.
// A2t: row-major [kx 0..17)[col f2, pad 134]; conflict-free b128 writes.
// LDS: A2 18.2K + Xc 16K = 34.4 KB -> 4 blocks/CU.
// Xf layout: [plane][kxi][ky][ri] (1024 dwords/plane). Scale 1/16384.
// ===========================================================================
__global__ __launch_bounds__(256, 4) void k_fwd(const float* __restrict__ X,
                                                float* __restrict__ Xf) {
  __shared__ __attribute__((aligned(16))) float A2t[17 * 134 * 2];  // 18.2 KB
  __shared__ __attribute__((aligned(16))) float Xc[4][8 * 128];     // 16 KB
  const int plane = blockIdx.x;
  const int tid = threadIdx.x;
  const float* Xp = X + (size_t)plane * (128 * 128);

  // ---- phase 1 ----
  {
    const int w2 = tid & 63;
    const int kxq = tid >> 6;             // wave-uniform
    const int lrow = tid >> 5;            // loader row 0..7
    const int col = (tid & 31) * 4;       // loader col (16B)

    float Wr[4], Wi[4], Tr[4], Ti[4];
    #pragma unroll
    for (int j = 0; j < 4; ++j) {
      int s = kxq * 4 + j;
      int kx = (s == 0) ? 16 : s;
      __sincosf(-PI2 * (float)kx / 128.f, &Wi[j], &Wr[j]);
      Tr[j] = 1.f; Ti[j] = 0.f;           // T_j(0)
    }
    float ar[4][2], ai[4][2];             // [slot j][col 0/1], const-indexed
    #pragma unroll
    for (int j = 0; j < 4; ++j) {
      ar[j][0] = 0.f; ar[j][1] = 0.f; ai[j][0] = 0.f; ai[j][1] = 0.f;
    }
    float dc0 = 0.f, dc1 = 0.f;

    // prologue: chunks 0,1,2 -> bufs 0,1,2 (depth-3 fill)
    {
      float4 v0, v1, v2;
      int r0g = (lrow < 4) ? lrow : (60 + lrow);
      int r1g = (lrow < 4) ? (4 + lrow) : (64 + lrow);
      int r2g = (lrow < 4) ? (8 + lrow) : (68 + lrow);
      v0 = *(const float4*)&Xp[r0g * 128 + col];
      v1 = *(const float4*)&Xp[r1g * 128 + col];
      v2 = *(const float4*)&Xp[r2g * 128 + col];
      *(float4*)&Xc[0][lrow * 128 + col] = v0;
      *(float4*)&Xc[1][lrow * 128 + col] = v1;
      *(float4*)&Xc[2][lrow * 128 + col] = v2;
    }
    __syncthreads();

    for (int c = 0; c < 16; ++c) {
      float4 nv;
      if (c < 13) {
        int rg = (lrow < 4) ? (4 * (c + 3) + lrow)
                            : (60 + 4 * (c + 3) + lrow);
        nv = *(const float4*)&Xp[rg * 128 + col];
      }
      const float* Xb = &Xc[c & 3][0];
      #pragma unroll
      for (int jj = 0; jj < 4; ++jj) {
        float2 tt = *(const float2*)&Xb[jj * 128 + 2 * w2];
        float2 bb = *(const float2*)&Xb[(jj + 4) * 128 + 2 * w2];
        float uex = tt.x + bb.x, uox = tt.x - bb.x;
        float uey = tt.y + bb.y, uoy = tt.y - bb.y;
        ar[0][0] = fmaf(uex, Tr[0], ar[0][0]); ai[0][0] = fmaf(uex, Ti[0], ai[0][0]);
        ar[0][1] = fmaf(uey, Tr[0], ar[0][1]); ai[0][1] = fmaf(uey, Ti[0], ai[0][1]);
        ar[1][0] = fmaf(uox, Tr[1], ar[1][0]); ai[1][0] = fmaf(uox, Ti[1], ai[1][0]);
        ar[1][1] = fmaf(uoy, Tr[1], ar[1][1]); ai[1][1] = fmaf(uoy, Ti[1], ai[1][1]);
        ar[2][0] = fmaf(uex, Tr[2], ar[2][0]); ai[2][0] = fmaf(uex, Ti[2], ai[2][0]);
        ar[2][1] = fmaf(uey, Tr[2], ar[2][1]); ai[2][1] = fmaf(uey, Ti[2], ai[2][1]);
        ar[3][0] = fmaf(uox, Tr[3], ar[3][0]); ai[3][0] = fmaf(uox, Ti[3], ai[3][0]);
        ar[3][1] = fmaf(uoy, Tr[3], ar[3][1]); ai[3][1] = fmaf(uoy, Ti[3], ai[3][1]);
        if (kxq == 0) { dc0 += uex; dc1 += uey; }   // wave-uniform branch
        #pragma unroll
        for (int j = 0; j < 4; ++j) {               // T_j *= W_j
          float nr = Tr[j] * Wr[j] - Ti[j] * Wi[j];
          float ni = Tr[j] * Wi[j] + Ti[j] * Wr[j];
          Tr[j] = nr; Ti[j] = ni;
        }
      }
      if (c == 7) {                                 // h=32: T_j = (-i)^j EXACT
        Tr[0] = 1.f;  Ti[0] = 0.f;
        Tr[1] = 0.f;  Ti[1] = -1.f;
        Tr[2] = -1.f; Ti[2] = 0.f;
        Tr[3] = 0.f;  Ti[3] = 1.f;
      }
      if (c < 13)
        *(float4*)&Xc[(c + 3) & 3][lrow * 128 + col] = nv;
      __syncthreads();
    }

    #pragma unroll
    for (int j = 0; j < 4; ++j) {
      int s = kxq * 4 + j;
      int row = (s == 0) ? 16 : s;
      *(float4*)&A2t[(row * 134 + 2 * w2) * 2] =
          make_float4(ar[j][0], ai[j][0], ar[j][1], ai[j][1]);
    }
    if (kxq == 0) {
      *(float4*)&A2t[(2 * w2) * 2] = make_float4(dc0, 0.f, dc1, 0.f);  // kx=0
    }
  }
  __syncthreads();

  // ---- phase 2: thread = (kxi 0..31, t 0..7); ky = {t, t+8} ----
  {
    const int kxi = tid >> 3;
    const int t = tid & 7;
    const int row = (kxi < 16) ? kxi : (32 - kxi);
    const float csign = (kxi < 16) ? 1.f : -1.f;   // conj for kxi>=16
    const float s = (t & 1) ? -1.f : 1.f;          // (-1)^ky
    float s0r, s0i, s1r, s1i;
    __sincosf(-PI2 * (float)t / 128.f, &s0i, &s0r);
    __sincosf(-PI2 * (float)(t + 8) / 128.f, &s1i, &s1r);
    float r0 = 0.f, i0 = 0.f, r1 = 0.f, i1 = 0.f;
    float E0r = 1.f, E0i = 0.f, E1r = 1.f, E1i = 0.f;
    #pragma unroll
    for (int half = 0; half < 2; ++half) {
      if (half == 1) {   // exact refresh: e^{-i pi t/2} == e^{-i pi (t+8)/2}
        float c_, s_;
        __sincosf(-1.57079632679489662f * (float)t, &s_, &c_);
        E0r = c_; E0i = s_; E1r = c_; E1i = s_;
      }
      #pragma unroll 4
      for (int w = half * 32; w < half * 32 + 32; ++w) {
        float2 a = *(const float2*)&A2t[(row * 134 + w) * 2];
        float2 b = *(const float2*)&A2t[(row * 134 + w + 64) * 2];
        float ur = fmaf(s, b.x, a.x);
        float ui = csign * fmaf(s, b.y, a.y);
        r0 = fmaf(ur, E0r, r0); r0 = fmaf(-ui, E0i, r0);
        i0 = fmaf(ur, E0i, i0); i0 = fmaf(ui, E0r, i0);
        r1 = fmaf(ur, E1r, r1); r1 = fmaf(-ui, E1i, r1);
        i1 = fmaf(ur, E1i, i1); i1 = fmaf(ui, E1r, i1);
        float u0 = E0r * s0r - E0i * s0i; E0i = E0r * s0i + E0i * s0r; E0r = u0;
        float u1 = E1r * s1r - E1i * s1i; E1i = E1r * s1i + E1i * s1r; E1r = u1;
      }
    }
    const float sc = 1.f / 16384.f;
    float* base = Xf + (size_t)plane * 1024 + kxi * 32;
    *(float2*)&base[t * 2]       = make_float2(r0 * sc, i0 * sc);
    *(float2*)&base[(t + 8) * 2] = make_float2(r1 * sc, i1 * sc);
  }
}

// ===========================================================================
// Kernel 2 (FUSED k_mix + k_inv): block = (b 16, c 64), grid 1024.
// Mix phase: thread tid owns modes {2tid, 2tid+1} (= dwords tid*4..tid*4+3
//   of the Y plane, exactly the Yl layout inv phase A expects).
//   Y[m] = sum_t w[c,t,m] * Xf[b,t,m]. Per t: one float4 Xf load (coalesced
//   1KB/wave) + two float2 weight loads (coalesced, wave-uniform corner).
//   Result written straight to Yl LDS -- deletes the Y global round-trip
//   (8 MB), one dispatch, and k_inv's Yl load. Xf re-read 64x / weights 16x
//   are L2/L3-resident (Xf 4 MB, weights 16 MB).
// Inv phases A/B: verbatim from the frozen k_inv (r2 structure).
// LDS: Yl 4K + Mt 16K = 20 KB.
// ===========================================================================
__global__ __launch_bounds__(256, 4) void k_mixinv(const float* __restrict__ Xf,
                                                   const float* __restrict__ w0r,
                                                   const float* __restrict__ w0i,
                                                   const float* __restrict__ w1r,
                                                   const float* __restrict__ w1i,
                                                   float* __restrict__ out) {
  __shared__ __attribute__((aligned(16))) float Yl[1024];
  __shared__ __attribute__((aligned(16))) float Mt[128 * 16 * 2];  // 16 KB
  const int bid = blockIdx.x;          // = b*64 + c  (== output plane index)
  const int b = bid >> 6;
  const int c = bid & 63;
  const int tid = threadIdx.x;

  // ---- mix phase ----
  {
    const int m0 = 2 * tid;            // first mode of this thread
    const int kxi = m0 >> 4;           // 0..31
    const int ky = m0 & 15;            // even
    const int x = (kxi < 16) ? kxi : (kxi - 16);
    const float* Wr = (kxi < 16) ? w0r : w1r;   // wave-uniform select
    const float* Wi = (kxi < 16) ? w0i : w1i;
    const float* xfp = Xf + ((size_t)b * 64) * 1024 + tid * 4;
    const size_t woff = ((size_t)c * 64 * 16 + x) * 16 + ky;
    const float* wrp = Wr + woff;
    const float* wip = Wi + woff;
    float yR0 = 0.f, yI0 = 0.f, yR1 = 0.f, yI1 = 0.f;
    #pragma unroll 4
    for (int t = 0; t < 64; ++t) {
      float4 xf = *(const float4*)&xfp[(size_t)t * 1024];  // modes m0, m0+1
      float2 wr = *(const float2*)&wrp[t * 256];           // (ky, ky+1)
      float2 wi = *(const float2*)&wip[t * 256];
      yR0 = fmaf(xf.x, wr.x, yR0); yR0 = fmaf(-xf.y, wi.x, yR0);
      yI0 = fmaf(xf.x, wi.x, yI0); yI0 = fmaf(xf.y, wr.x, yI0);
      yR1 = fmaf(xf.z, wr.y, yR1); yR1 = fmaf(-xf.w, wi.y, yR1);
      yI1 = fmaf(xf.z, wi.y, yI1); yI1 = fmaf(xf.w, wr.y, yI1);
    }
    *(float4*)&Yl[tid * 4] = make_float4(yR0, yI0, yR1, yI1);
  }
  __syncthreads();

  // ---- phase A (verbatim k_inv) ----
  {
    const int g = tid >> 6;          // ky quad: ky = 4g..4g+3 (wave-uniform)
    const int h2 = tid & 63;
    float zr[2][4] = {}, zi[2][4] = {};   // [h-sel][ky j]
    float uw, uwi;                   // U = e^{+2pi i h2/128}
    __sincosf(PI2 * (float)h2 / 128.f, &uwi, &uw);
    const float4* Yl4 = (const float4*)Yl;
    float Tr = 1.f, Ti = 0.f;
    #pragma unroll 4
    for (int kxi = 0; kxi < 16; ++kxi) {
      float sgn = (kxi & 1) ? -1.f : 1.f;    // (-1)^kx for h2+64
      #pragma unroll
      for (int q = 0; q < 2; ++q) {
        float4 p = Yl4[kxi * 8 + g * 2 + q];
        float cr0 = p.x * Tr - p.y * Ti, ci0 = p.x * Ti + p.y * Tr;
        float cr1 = p.z * Tr - p.w * Ti, ci1 = p.z * Ti + p.w * Tr;
        zr[0][2*q]   += cr0; zi[0][2*q]   += ci0;
        zr[0][2*q+1] += cr1; zi[0][2*q+1] += ci1;
        zr[1][2*q]   = fmaf(sgn, cr0, zr[1][2*q]);   zi[1][2*q]   = fmaf(sgn, ci0, zi[1][2*q]);
        zr[1][2*q+1] = fmaf(sgn, cr1, zr[1][2*q+1]); zi[1][2*q+1] = fmaf(sgn, ci1, zi[1][2*q+1]);
      }
      float nr = Tr * uw - Ti * uwi, ni = Tr * uwi + Ti * uw;
      Tr = nr; Ti = ni;
    }
    __sincosf(PI2 * (float)((112 * h2) & 127) / 128.f, &Ti, &Tr);
    #pragma unroll 4
    for (int kxi = 16; kxi < 32; ++kxi) {
      float sgn = (kxi & 1) ? -1.f : 1.f;
      #pragma unroll
      for (int q = 0; q < 2; ++q) {
        float4 p = Yl4[kxi * 8 + g * 2 + q];
        float cr0 = p.x * Tr - p.y * Ti, ci0 = p.x * Ti + p.y * Tr;
        float cr1 = p.z * Tr - p.w * Ti, ci1 = p.z * Ti + p.w * Tr;
        zr[0][2*q]   += cr0; zi[0][2*q]   += ci0;
        zr[0][2*q+1] += cr1; zi[0][2*q+1] += ci1;
        zr[1][2*q]   = fmaf(sgn, cr0, zr[1][2*q]);   zi[1][2*q]   = fmaf(sgn, ci0, zi[1][2*q]);
        zr[1][2*q+1] = fmaf(sgn, cr1, zr[1][2*q+1]); zi[1][2*q+1] = fmaf(sgn, ci1, zi[1][2*q+1]);
      }
      float nr = Tr * uw - Ti * uwi, ni = Tr * uwi + Ti * uw;
      Tr = nr; Ti = ni;
    }
    #pragma unroll
    for (int hs = 0; hs < 2; ++hs) {
      int h = h2 + hs * 64;
      #pragma unroll
      for (int q = 0; q < 2; ++q) {
        int ky0 = g * 4 + 2 * q;
        float f0 = (ky0 == 0) ? 1.f : 2.f;
        float4 v = make_float4(f0 * zr[hs][2*q],   -f0 * zi[hs][2*q],
                               2.f * zr[hs][2*q+1], -2.f * zi[hs][2*q+1]);
        int f4i = h * 8 + ((g * 2 + q) ^ (h & 7));
        *(float4*)&Mt[f4i * 4] = v;
      }
    }
  }
  __syncthreads();

  // ---- phase B (verbatim k_inv) ----
  {
    const int hp = tid >> 5;        // 0..7
    const int w2 = tid & 31;        // 0..31
    float C[16], S[16];
    {
      float cw, sw;
      __sincosf(PI2 * (float)w2 / 128.f, &sw, &cw);
      C[0] = 1.f; S[0] = 0.f;
      #pragma unroll
      for (int k = 1; k < 16; ++k) {
        C[k] = C[k - 1] * cw - S[k - 1] * sw;
        S[k] = C[k - 1] * sw + S[k - 1] * cw;
      }
    }
    float* op = out + (size_t)bid * (128 * 128);
    const float4* Mt4 = (const float4*)Mt;
    #pragma unroll 4
    for (int hj = 0; hj < 16; ++hj) {
      int h = hp * 16 + hj;
      float e = 0.f, o = 0.f, e2 = 0.f, o2 = 0.f;
      #pragma unroll
      for (int j = 0; j < 8; ++j) {
        float4 m = Mt4[h * 8 + (j ^ (h & 7))];   // (Mc,Ms) ky=2j | ky=2j+1
        int k0 = 2 * j, k1 = 2 * j + 1;
        e = fmaf(m.x, C[k0], e); e = fmaf(m.y, S[k0], e);
        o = fmaf(m.z, C[k1], o); o = fmaf(m.w, S[k1], o);
        if ((k0 & 2) == 0) { e2 = fmaf(m.x, C[k0], e2); e2 = fmaf(m.y, S[k0], e2); }
        else               { e2 = fmaf(-m.x, C[k0], e2); e2 = fmaf(-m.y, S[k0], e2); }
        if ((k1 & 2) == 0) { o2 = fmaf(m.w, C[k1], o2); o2 = fmaf(-m.z, S[k1], o2); }
        else               { o2 = fmaf(-m.w, C[k1], o2); o2 = fmaf(m.z, S[k1], o2); }
      }
      op[h * 128 + w2]      = e + o;
      op[h * 128 + w2 + 64] = e - o;
      op[h * 128 + w2 + 32] = e2 + o2;
      op[h * 128 + w2 + 96] = e2 - o2;
    }
  }
}

extern "C" void kernel_launch(void* const* d_in, const int* in_sizes, int n_in,
                              void* d_out, int out_size, void* d_ws, size_t ws_size,
                              hipStream_t stream) {
  const float* X   = (const float*)d_in[0];
  const float* w0r = (const float*)d_in[1];
  const float* w0i = (const float*)d_in[2];
  const float* w1r = (const float*)d_in[3];
  const float* w1i = (const float*)d_in[4];
  float* outp = (float*)d_out;
  float* Xf = (float*)d_ws;                  // 4 MB
  k_fwd<<<1024, 256, 0, stream>>>(X, Xf);
  k_mixinv<<<1024, 256, 0, stream>>>(Xf, w0r, w0i, w1r, w1i, outp);
}

// Round 11
// 162.454 us; speedup vs baseline: 1.1049x; 1.1049x over previous
//
#include <hip/hip_runtime.h>

#define PI2 6.28318530717958647692f

// ===========================================================================
// BEST-MEASURED CONFIGURATION (round-5 run: 160.955 us total; k_fwd 41.5us,
// k_mix/k_inv below the 41us fill entries). Later variants (register
// twiddles 166.6, depth-3 ring 169.5, mix+inv fusion 179.5) were all
// neutral-to-negative; this locks in the measured optimum. (r10 run was an
// infra failure -- "container failed twice" -- resubmitting unchanged.)
//
// Kernel 1: per (b,t) plane forward DFT restricted to kept modes.
// Conjugate symmetry: X real => A2[128-kx][w] = conj(A2[kx][w]): phase 1
// computes kx = 0..16 only; phase 2 derives kxi>=16 by conjugation.
// Phase 1 (LDS-staged X): block streams its plane through LDS in 16
//   chunks of 8 rows (4 top rows 4c..4c+3 + their fold partners +64).
//   Reg-staged double buffer: load chunk c+1 (float4/thread, coalesced)
//   -> compute chunk c from LDS -> ds_write_b128 -> __syncthreads().
//   thread = (w2 0..63, kxq 0..3): cols {2w2,2w2+1}, kx slot group kxq
//   (slot0 = kx16, slot k = kx k; kxq0 also accumulates DC kx=0).
// Phase 2: thread = (kxi 0..31, t 0..7); ky = {t,t+8}; ky-twiddles in
//   registers, advanced by complex step, exact refresh at w=32. No E2 table.
// A2t layout: row-major [kx 0..17)[col f2, pad 134]; b128 writes at
//   16B/lane (conflict-free, 0 measured). Tt: [h<64][slot<16] f2 (8 KB).
// LDS: A2 18.2K + Tt 8K + Xc 8K = 34.4 KB -> 4 blocks/CU.
// Xf layout: [plane][kxi][ky][ri] (1024 dwords/plane). Scale 1/16384.
// ===========================================================================
__global__ __launch_bounds__(256, 4) void k_fwd(const float* __restrict__ X,
                                                float* __restrict__ Xf) {
  __shared__ __attribute__((aligned(16))) float A2t[17 * 134 * 2];  // 18.2 KB
  __shared__ __attribute__((aligned(16))) float Tt[64 * 16 * 2];    // 8 KB
  __shared__ __attribute__((aligned(16))) float Xc[2][8 * 128];     // 8 KB
  const int plane = blockIdx.x;
  const int tid = threadIdx.x;
  const float* Xp = X + (size_t)plane * (128 * 128);

  // ---- E1 table: Tt[h][slot]: slot0 -> kx=16, slot k -> kx=k (1..15) ----
  #pragma unroll
  for (int k = 0; k < 4; ++k) {
    int idx = tid + k * 256;              // 1024 entries
    int h = idx >> 4, slot = idx & 15;
    int kx = slot ? slot : 16;
    float ang = -PI2 * (float)((kx * h) & 127) / 128.f;
    float s_, c_;
    __sincosf(ang, &s_, &c_);
    Tt[idx * 2] = c_; Tt[idx * 2 + 1] = s_;
  }

  // ---- phase 1 ----
  {
    const int w2 = tid & 63;
    const int kxq = tid >> 6;             // wave-uniform
    // loader mapping: thread -> 16B of the 4KB chunk
    const int lrow = tid >> 5;            // 0..7 (0-3 top, 4-7 bottom)
    const int lcol = (tid & 31) * 4;      // 0..124
    float ar[4][2], ai[4][2];             // [slot j][col 0/1], const-indexed
    #pragma unroll
    for (int j = 0; j < 4; ++j) {
      ar[j][0] = 0.f; ar[j][1] = 0.f; ai[j][0] = 0.f; ai[j][1] = 0.f;
    }
    float dc0 = 0.f, dc1 = 0.f;

    // prologue: chunk 0 -> buf 0 (also covers the E1-table barrier)
    {
      int rg = (lrow < 4) ? lrow : (60 + lrow);   // rows 0..3 / 64..67
      float4 v = *(const float4*)&Xp[rg * 128 + lcol];
      *(float4*)&Xc[0][lrow * 128 + lcol] = v;
    }
    __syncthreads();

#define ROWSTEP(HH, JJ, XB) do {                                             \
    float2 tt_ = *(const float2*)&(XB)[(JJ) * 128 + 2 * w2];                 \
    float2 bb_ = *(const float2*)&(XB)[((JJ) + 4) * 128 + 2 * w2];           \
    float uex_ = tt_.x + bb_.x, uox_ = tt_.x - bb_.x;                        \
    float uey_ = tt_.y + bb_.y, uoy_ = tt_.y - bb_.y;                        \
    const float4* Trow_ = (const float4*)&Tt[(HH) * 32];                     \
    float4 e01_ = Trow_[kxq * 2];        /* slots 4q (even kx), 4q+1 (odd) */\
    float4 e23_ = Trow_[kxq * 2 + 1];    /* slots 4q+2 (even), 4q+3 (odd) */ \
    ar[0][0] = fmaf(uex_, e01_.x, ar[0][0]); ai[0][0] = fmaf(uex_, e01_.y, ai[0][0]); \
    ar[0][1] = fmaf(uey_, e01_.x, ar[0][1]); ai[0][1] = fmaf(uey_, e01_.y, ai[0][1]); \
    ar[1][0] = fmaf(uox_, e01_.z, ar[1][0]); ai[1][0] = fmaf(uox_, e01_.w, ai[1][0]); \
    ar[1][1] = fmaf(uoy_, e01_.z, ar[1][1]); ai[1][1] = fmaf(uoy_, e01_.w, ai[1][1]); \
    ar[2][0] = fmaf(uex_, e23_.x, ar[2][0]); ai[2][0] = fmaf(uex_, e23_.y, ai[2][0]); \
    ar[2][1] = fmaf(uey_, e23_.x, ar[2][1]); ai[2][1] = fmaf(uey_, e23_.y, ai[2][1]); \
    ar[3][0] = fmaf(uox_, e23_.z, ar[3][0]); ai[3][0] = fmaf(uox_, e23_.w, ai[3][0]); \
    ar[3][1] = fmaf(uoy_, e23_.z, ar[3][1]); ai[3][1] = fmaf(uoy_, e23_.w, ai[3][1]); \
    if (kxq == 0) { dc0 += uex_; dc1 += uey_; }      /* wave-uniform */      \
  } while (0)

    for (int c = 0; c < 16; ++c) {
      // issue next chunk's load early (consumed after compute, ~200cy cover)
      float4 nv;
      if (c < 15) {
        int rg = (lrow < 4) ? (4 * (c + 1) + lrow) : (60 + 4 * (c + 1) + lrow);
        nv = *(const float4*)&Xp[rg * 128 + lcol];
      }
      const float* Xb = &Xc[c & 1][0];
      ROWSTEP(4 * c,     0, Xb);
      ROWSTEP(4 * c + 1, 1, Xb);
      ROWSTEP(4 * c + 2, 2, Xb);
      ROWSTEP(4 * c + 3, 3, Xb);
      if (c < 15)
        *(float4*)&Xc[(c + 1) & 1][lrow * 128 + lcol] = nv;
      __syncthreads();   // all reads of buf c done; chunk c+1 visible
    }
#undef ROWSTEP

    // A2 store: b128 at 16B/lane stride (conflict-free). row = kx.
    #pragma unroll
    for (int j = 0; j < 4; ++j) {
      int s = kxq * 4 + j;
      int row = (s == 0) ? 16 : s;
      *(float4*)&A2t[(row * 134 + 2 * w2) * 2] =
          make_float4(ar[j][0], ai[j][0], ar[j][1], ai[j][1]);
    }
    if (kxq == 0) {
      *(float4*)&A2t[(2 * w2) * 2] = make_float4(dc0, 0.f, dc1, 0.f);  // kx=0
    }
  }
  __syncthreads();

  // ---- phase 2: thread = (kxi 0..31, t 0..7); ky = {t, t+8} ----
  {
    const int kxi = tid >> 3;
    const int t = tid & 7;
    const int row = (kxi < 16) ? kxi : (32 - kxi);
    const float csign = (kxi < 16) ? 1.f : -1.f;   // conj for kxi>=16
    const float s = (t & 1) ? -1.f : 1.f;          // (-1)^ky
    float s0r, s0i, s1r, s1i;
    __sincosf(-PI2 * (float)t / 128.f, &s0i, &s0r);
    __sincosf(-PI2 * (float)(t + 8) / 128.f, &s1i, &s1r);
    float r0 = 0.f, i0 = 0.f, r1 = 0.f, i1 = 0.f;
    float E0r = 1.f, E0i = 0.f, E1r = 1.f, E1i = 0.f;
    #pragma unroll
    for (int half = 0; half < 2; ++half) {
      if (half == 1) {   // exact refresh: e^{-i pi t/2} == e^{-i pi (t+8)/2}
        float c_, s_;
        __sincosf(-1.57079632679489662f * (float)t, &s_, &c_);
        E0r = c_; E0i = s_; E1r = c_; E1i = s_;
      }
      for (int w = half * 32; w < half * 32 + 32; ++w) {
        float2 a = *(const float2*)&A2t[(row * 134 + w) * 2];
        float2 b = *(const float2*)&A2t[(row * 134 + w + 64) * 2];
        float ur = fmaf(s, b.x, a.x);
        float ui = csign * fmaf(s, b.y, a.y);
        r0 = fmaf(ur, E0r, r0); r0 = fmaf(-ui, E0i, r0);
        i0 = fmaf(ur, E0i, i0); i0 = fmaf(ui, E0r, i0);
        r1 = fmaf(ur, E1r, r1); r1 = fmaf(-ui, E1i, r1);
        i1 = fmaf(ur, E1i, i1); i1 = fmaf(ui, E1r, i1);
        float u0 = E0r * s0r - E0i * s0i; E0i = E0r * s0i + E0i * s0r; E0r = u0;
        float u1 = E1r * s1r - E1i * s1i; E1i = E1r * s1i + E1i * s1r; E1r = u1;
      }
    }
    const float sc = 1.f / 16384.f;
    float* base = Xf + (size_t)plane * 1024 + kxi * 32;
    *(float2*)&base[t * 2]       = make_float2(r0 * sc, i0 * sc);
    *(float2*)&base[(t + 8) * 2] = make_float2(r1 * sc, i1 * sc);
  }
}

// ===========================================================================
// Kernel 2: channel mix. block = (corner 2, x 16, cg 16), c-tile of 4.
// grid 512. Weights packed (t even, t odd) per float4 -> b128 LDS reads.
// thread = (b 16, y 16). Y[b][c][kxi][ky][ri], same layout as Xf.
// (FROZEN at the round-2 configuration; best-measured run.)
// ===========================================================================
__global__ __launch_bounds__(256, 2) void k_mix(const float* __restrict__ Xf,
                                                const float* __restrict__ w0r,
                                                const float* __restrict__ w0i,
                                                const float* __restrict__ w1r,
                                                const float* __restrict__ w1i,
                                                float* __restrict__ Y) {
  __shared__ __attribute__((aligned(16))) float Wl[4 * 32 * 16 * 4]; // 32 KB
  const int bid = blockIdx.x;               // 0..511
  const int c2 = bid >> 8;
  const int x  = (bid >> 4) & 15;
  const int cg = bid & 15;
  const int c0 = cg * 4;
  const int kxi = c2 * 16 + x;
  const float* Wr_g = c2 ? w1r : w0r;
  const float* Wi_g = c2 ? w1i : w0i;
  const int tid = threadIdx.x;
  const int b = tid >> 4;
  const int y = tid & 15;

  // stage: 4096 complex; Wl f4[(c*32 + t/2)*16 + y] = (wr_e, wi_e, wr_o, wi_o)
  #pragma unroll
  for (int k = 0; k < 16; ++k) {
    int idx = tid + k * 256;                // 0..4095
    int y_ = idx & 15, t_ = (idx >> 4) & 63, c_ = idx >> 10;
    size_t ga = (((size_t)(c0 + c_) * 64 + t_) * 16 + x) * 16 + y_;
    int f2i = ((c_ * 32 + (t_ >> 1)) * 16 + y_) * 2 + (t_ & 1);
    *(float2*)&Wl[f2i * 2] = make_float2(Wr_g[ga], Wi_g[ga]);
  }
  __syncthreads();

  float aR[4] = {}, aI[4] = {};
  const float* xbase = Xf + ((size_t)b * 64) * 1024 + kxi * 32 + y * 2;
  for (int t8 = 0; t8 < 64; t8 += 8) {
    float2 xv[8];
    #pragma unroll
    for (int q = 0; q < 8; ++q)
      xv[q] = *(const float2*)&xbase[(size_t)(t8 + q) * 1024];
    #pragma unroll
    for (int p = 0; p < 4; ++p) {           // t2 pair index
      int t2 = (t8 >> 1) + p;
      float2 xe = xv[2 * p], xo = xv[2 * p + 1];
      #pragma unroll
      for (int cj = 0; cj < 4; ++cj) {
        float4 wv = *(const float4*)&Wl[((cj * 32 + t2) * 16 + y) * 4];
        aR[cj] = fmaf(xe.x, wv.x, aR[cj]); aR[cj] = fmaf(-xe.y, wv.y, aR[cj]);
        aI[cj] = fmaf(xe.x, wv.y, aI[cj]); aI[cj] = fmaf(xe.y, wv.x, aI[cj]);
        aR[cj] = fmaf(xo.x, wv.z, aR[cj]); aR[cj] = fmaf(-xo.y, wv.w, aR[cj]);
        aI[cj] = fmaf(xo.x, wv.w, aI[cj]); aI[cj] = fmaf(xo.y, wv.z, aI[cj]);
      }
    }
  }
  #pragma unroll
  for (int cj = 0; cj < 4; ++cj) {
    size_t ya = ((size_t)(b * 64 + c0 + cj)) * 1024 + kxi * 32 + y * 2;
    *(float2*)&Y[ya] = make_float2(aR[cj], aI[cj]);
  }
}

// ===========================================================================
// Kernel 3: per (b,c) plane inverse.  (FROZEN at round-2 structure;
// best-measured run.)
// Phase A: thread = (g 0..3 ky-quad, h2 0..63); handles h in {h2, h2+64}
//   via sign (-1)^kx on the shared twiddle. Stores Mt f4-packed with XOR
//   swizzle: f4idx = h*8 + (j ^ (h&7))  (write-conflict-free).
// Phase B: thread = (hp 0..7, w2 0..31); 16 h each, outputs w2, w2+32,
//   w2+64, w2+96. The w2+32 twiddles are the i^k register rotation of w2's
//   C/S; the +64 fold uses ky parity.
// ===========================================================================
__global__ __launch_bounds__(256, 4) void k_inv(const float* __restrict__ Y,
                                                float* __restrict__ out) {
  __shared__ __attribute__((aligned(16))) float Yl[1024];
  __shared__ __attribute__((aligned(16))) float Mt[128 * 16 * 2];  // 16 KB
  const int plane = blockIdx.x;
  const int tid = threadIdx.x;
  *(float4*)&Yl[tid * 4] = *(const float4*)&Y[(size_t)plane * 1024 + tid * 4];
  __syncthreads();

  // ---- phase A ----
  {
    const int g = tid >> 6;          // ky quad: ky = 4g..4g+3 (wave-uniform)
    const int h2 = tid & 63;
    float zr[2][4] = {}, zi[2][4] = {};   // [h-sel][ky j]
    float uw, uwi;                   // U = e^{+2pi i h2/128}
    __sincosf(PI2 * (float)h2 / 128.f, &uwi, &uw);
    const float4* Yl4 = (const float4*)Yl;
    float Tr = 1.f, Ti = 0.f;
    #pragma unroll 2
    for (int kxi = 0; kxi < 16; ++kxi) {
      float sgn = (kxi & 1) ? -1.f : 1.f;    // (-1)^kx for h2+64
      #pragma unroll
      for (int q = 0; q < 2; ++q) {
        float4 p = Yl4[kxi * 8 + g * 2 + q];
        float cr0 = p.x * Tr - p.y * Ti, ci0 = p.x * Ti + p.y * Tr;
        float cr1 = p.z * Tr - p.w * Ti, ci1 = p.z * Ti + p.w * Tr;
        zr[0][2*q]   += cr0; zi[0][2*q]   += ci0;
        zr[0][2*q+1] += cr1; zi[0][2*q+1] += ci1;
        zr[1][2*q]   = fmaf(sgn, cr0, zr[1][2*q]);   zi[1][2*q]   = fmaf(sgn, ci0, zi[1][2*q]);
        zr[1][2*q+1] = fmaf(sgn, cr1, zr[1][2*q+1]); zi[1][2*q+1] = fmaf(sgn, ci1, zi[1][2*q+1]);
      }
      float nr = Tr * uw - Ti * uwi, ni = Tr * uwi + Ti * uw;
      Tr = nr; Ti = ni;
    }
    __sincosf(PI2 * (float)((112 * h2) & 127) / 128.f, &Ti, &Tr);
    #pragma unroll 2
    for (int kxi = 16; kxi < 32; ++kxi) {
      float sgn = (kxi & 1) ? -1.f : 1.f;
      #pragma unroll
      for (int q = 0; q < 2; ++q) {
        float4 p = Yl4[kxi * 8 + g * 2 + q];
        float cr0 = p.x * Tr - p.y * Ti, ci0 = p.x * Ti + p.y * Tr;
        float cr1 = p.z * Tr - p.w * Ti, ci1 = p.z * Ti + p.w * Tr;
        zr[0][2*q]   += cr0; zi[0][2*q]   += ci0;
        zr[0][2*q+1] += cr1; zi[0][2*q+1] += ci1;
        zr[1][2*q]   = fmaf(sgn, cr0, zr[1][2*q]);   zi[1][2*q]   = fmaf(sgn, ci0, zi[1][2*q]);
        zr[1][2*q+1] = fmaf(sgn, cr1, zr[1][2*q+1]); zi[1][2*q+1] = fmaf(sgn, ci1, zi[1][2*q+1]);
      }
      float nr = Tr * uw - Ti * uwi, ni = Tr * uwi + Ti * uw;
      Tr = nr; Ti = ni;
    }
    #pragma unroll
    for (int hs = 0; hs < 2; ++hs) {
      int h = h2 + hs * 64;
      #pragma unroll
      for (int q = 0; q < 2; ++q) {
        int ky0 = g * 4 + 2 * q;
        float f0 = (ky0 == 0) ? 1.f : 2.f;
        float4 v = make_float4(f0 * zr[hs][2*q],   -f0 * zi[hs][2*q],
                               2.f * zr[hs][2*q+1], -2.f * zi[hs][2*q+1]);
        int f4i = h * 8 + ((g * 2 + q) ^ (h & 7));
        *(float4*)&Mt[f4i * 4] = v;
      }
    }
  }
  __syncthreads();

  // ---- phase B ----
  {
    const int hp = tid >> 5;        // 0..7
    const int w2 = tid & 31;        // 0..31
    float C[16], S[16];
    {
      float cw, sw;
      __sincosf(PI2 * (float)w2 / 128.f, &sw, &cw);
      C[0] = 1.f; S[0] = 0.f;
      #pragma unroll
      for (int k = 1; k < 16; ++k) {
        C[k] = C[k - 1] * cw - S[k - 1] * sw;
        S[k] = C[k - 1] * sw + S[k - 1] * cw;
      }
    }
    float* op = out + (size_t)plane * (128 * 128);
    const float4* Mt4 = (const float4*)Mt;
    #pragma unroll 2
    for (int hj = 0; hj < 16; ++hj) {
      int h = hp * 16 + hj;
      float e = 0.f, o = 0.f, e2 = 0.f, o2 = 0.f;
      #pragma unroll
      for (int j = 0; j < 8; ++j) {
        float4 m = Mt4[h * 8 + (j ^ (h & 7))];   // (Mc,Ms) ky=2j | ky=2j+1
        int k0 = 2 * j, k1 = 2 * j + 1;
        e = fmaf(m.x, C[k0], e); e = fmaf(m.y, S[k0], e);
        o = fmaf(m.z, C[k1], o); o = fmaf(m.w, S[k1], o);
        // w2+32: cos(th+pi k/2), sin(th+pi k/2) rotations
        if ((k0 & 2) == 0) { e2 = fmaf(m.x, C[k0], e2); e2 = fmaf(m.y, S[k0], e2); }
        else               { e2 = fmaf(-m.x, C[k0], e2); e2 = fmaf(-m.y, S[k0], e2); }
        if ((k1 & 2) == 0) { o2 = fmaf(m.w, C[k1], o2); o2 = fmaf(-m.z, S[k1], o2); }
        else               { o2 = fmaf(-m.w, C[k1], o2); o2 = fmaf(m.z, S[k1], o2); }
      }
      op[h * 128 + w2]      = e + o;
      op[h * 128 + w2 + 64] = e - o;
      op[h * 128 + w2 + 32] = e2 + o2;
      op[h * 128 + w2 + 96] = e2 - o2;
    }
  }
}

extern "C" void kernel_launch(void* const* d_in, const int* in_sizes, int n_in,
                              void* d_out, int out_size, void* d_ws, size_t ws_size,
                              hipStream_t stream) {
  const float* X   = (const float*)d_in[0];
  const float* w0r = (const float*)d_in[1];
  const float* w0i = (const float*)d_in[2];
  const float* w1r = (const float*)d_in[3];
  const float* w1i = (const float*)d_in[4];
  float* outp = (float*)d_out;
  float* Xf = (float*)d_ws;                  // 4 MB
  float* Yw = (float*)d_ws + (1u << 20);     // 4 MB
  k_fwd<<<1024, 256, 0, stream>>>(X, Xf);
  k_mix<<<512, 256, 0, stream>>>(Xf, w0r, w0i, w1r, w1i, Yw);
  k_inv<<<1024, 256, 0, stream>>>(Yw, outp);
}